// Round 1
// baseline (807.289 us; speedup 1.0000x reference)
//
#include <hip/hip_runtime.h>

#define NN 100000
#define EE 1600000
#define DD 128

static __device__ __forceinline__ float dot4(float4 a, float4 b) {
  return a.x * b.x + a.y * b.y + a.z * b.z + a.w * b.w;
}

// ---- degree counting (int atomics, L2-resident counters) ----
__global__ __launch_bounds__(256) void count_k(const int* __restrict__ src,
                                               const int* __restrict__ dst,
                                               int* __restrict__ cs, int* __restrict__ cd) {
  int i = blockIdx.x * 256 + threadIdx.x;
  if (i < EE) {
    atomicAdd(&cs[src[i]], 1);
    atomicAdd(&cd[dst[i]], 1);
  }
}

// ---- norm = clip(deg,1)^-0.5 ----
__global__ __launch_bounds__(256) void norm_k(const int* __restrict__ cs,
                                              const int* __restrict__ cd,
                                              float* __restrict__ no, float* __restrict__ ni) {
  int i = blockIdx.x * 256 + threadIdx.x;
  if (i < NN) {
    int a = cs[i] > 1 ? cs[i] : 1;
    int b = cd[i] > 1 ? cd[i] : 1;
    no[i] = rsqrtf((float)a);
    ni[i] = rsqrtf((float)b);
  }
}

// ---- scan phase 1: per-1024-chunk exclusive scan + block sums ----
__global__ __launch_bounds__(256) void scan1_k(const int* __restrict__ cnt,
                                               int* __restrict__ excl, int* __restrict__ bsums) {
  __shared__ int lds[256];
  int t = threadIdx.x;
  int base = blockIdx.x * 1024 + t * 4;
  int v0 = (base + 0 < NN) ? cnt[base + 0] : 0;
  int v1 = (base + 1 < NN) ? cnt[base + 1] : 0;
  int v2 = (base + 2 < NN) ? cnt[base + 2] : 0;
  int v3 = (base + 3 < NN) ? cnt[base + 3] : 0;
  int s = v0 + v1 + v2 + v3;
  lds[t] = s;
  __syncthreads();
  int run = s;
  for (int off = 1; off < 256; off <<= 1) {
    int y = (t >= off) ? lds[t - off] : 0;
    __syncthreads();
    run += y;
    lds[t] = run;
    __syncthreads();
  }
  if (t == 255) bsums[blockIdx.x] = run;  // block total
  int ex = run - s;                       // exclusive prefix within block
  if (base + 0 < NN) excl[base + 0] = ex; ex += v0;
  if (base + 1 < NN) excl[base + 1] = ex; ex += v1;
  if (base + 2 < NN) excl[base + 2] = ex; ex += v2;
  if (base + 3 < NN) excl[base + 3] = ex;
}

// ---- scan phase 2: exclusive scan of the 98 block sums (single block) ----
__global__ __launch_bounds__(128) void scan2_k(int* __restrict__ bsums) {
  __shared__ int lds[128];
  int t = threadIdx.x;
  int s = (t < 98) ? bsums[t] : 0;
  lds[t] = s;
  __syncthreads();
  int run = s;
  for (int off = 1; off < 128; off <<= 1) {
    int y = (t >= off) ? lds[t - off] : 0;
    __syncthreads();
    run += y;
    lds[t] = run;
    __syncthreads();
  }
  if (t < 98) bsums[t] = run - s;  // exclusive
}

// ---- CSR fill: csr bucket of dst node gets src ids ----
__global__ __launch_bounds__(256) void fill_k(const int* __restrict__ src,
                                              const int* __restrict__ dst,
                                              const int* __restrict__ excl,
                                              const int* __restrict__ bsums,
                                              int* __restrict__ cursor, int* __restrict__ csr) {
  int i = blockIdx.x * 256 + threadIdx.x;
  if (i < EE) {
    int d = dst[i];
    int pos = atomicAdd(&cursor[d], 1);
    csr[excl[d] + bsums[d >> 10] + pos] = src[i];
  }
}

// ---- aggregation: half-wave (32 lanes x float4) per dst node, atomic-free ----
__global__ __launch_bounds__(256) void aggregate_k(const float* __restrict__ fin,
                                                   const float* __restrict__ nsrc,
                                                   const int* __restrict__ csr,
                                                   const int* __restrict__ excl,
                                                   const int* __restrict__ bsums,
                                                   float* __restrict__ outp) {
  int node = (blockIdx.x * 256 + threadIdx.x) >> 5;
  int lane = threadIdx.x & 31;
  if (node >= NN) return;
  int e0 = excl[node] + bsums[node >> 10];
  int e1 = (node == NN - 1) ? EE : (excl[node + 1] + bsums[(node + 1) >> 10]);
  float ax = 0.f, ay = 0.f, az = 0.f, aw = 0.f;
  int e = e0;
  // unroll by 2 to keep 2 row-loads in flight
  for (; e + 2 <= e1; e += 2) {
    int s0 = csr[e];
    int s1 = csr[e + 1];
    float n0 = nsrc[s0];
    float n1 = nsrc[s1];
    float4 u = *reinterpret_cast<const float4*>(fin + s0 * DD + (lane << 2));
    float4 v = *reinterpret_cast<const float4*>(fin + s1 * DD + (lane << 2));
    ax += u.x * n0 + v.x * n1;
    ay += u.y * n0 + v.y * n1;
    az += u.z * n0 + v.z * n1;
    aw += u.w * n0 + v.w * n1;
  }
  if (e < e1) {
    int s0 = csr[e];
    float n0 = nsrc[s0];
    float4 u = *reinterpret_cast<const float4*>(fin + s0 * DD + (lane << 2));
    ax += u.x * n0;
    ay += u.y * n0;
    az += u.z * n0;
    aw += u.w * n0;
  }
  *reinterpret_cast<float4*>(outp + node * DD + (lane << 2)) = make_float4(ax, ay, az, aw);
}

// ---- fused GEMM + epilogue: out = act((agg @ W^T + b) * norm_in + resid) ----
// In-place safe: each block stages its own 32 rows into LDS before any write.
// Two passes over j (64 cols each) keep LDS at 32KB(W) + 16KB(rows) = 48KB.
__global__ __launch_bounds__(256) void gemm_k(const float* __restrict__ agg,
                                              const float* __restrict__ W,
                                              const float* __restrict__ bias,
                                              const float* __restrict__ nin,
                                              const float* __restrict__ resid,
                                              float* __restrict__ outp, int mode) {
  __shared__ float4 Wl[64 * 32];     // 64 rows of W, float4 over k (32KB)
  __shared__ float4 Rw[8][4][32];    // 8 half-waves x 4 rows x 128 floats (16KB)
  int t = threadIdx.x;
  int hw = t >> 5;
  int lane = t & 31;
  int rbase = blockIdx.x * 32 + hw * 4;

  // stage this half-wave's 4 rows (grid is exact: 3125*32 == 100000)
  for (int r = 0; r < 4; ++r) {
    Rw[hw][r][lane] = *reinterpret_cast<const float4*>(agg + (rbase + r) * DD + (lane << 2));
  }

  for (int p = 0; p < 2; ++p) {
    __syncthreads();  // rows staged (p==0) / all waves done with previous Wl (p==1)
    const float4* Wg = reinterpret_cast<const float4*>(W) + p * (64 * 32);
    for (int i = t; i < 64 * 32; i += 256) Wl[i] = Wg[i];
    __syncthreads();

    float acc[4][2];
#pragma unroll
    for (int r = 0; r < 4; ++r) { acc[r][0] = 0.f; acc[r][1] = 0.f; }

#pragma unroll 4
    for (int tt = 0; tt < 32; ++tt) {
      int k4 = (tt + lane) & 31;  // rotation keeps all LDS reads conflict-free
      float4 a0 = Rw[hw][0][k4];
      float4 a1 = Rw[hw][1][k4];
      float4 a2 = Rw[hw][2][k4];
      float4 a3 = Rw[hw][3][k4];
      float4 wA = Wl[(lane << 5) + k4];
      float4 wB = Wl[((lane + 32) << 5) + k4];
      acc[0][0] += dot4(a0, wA); acc[0][1] += dot4(a0, wB);
      acc[1][0] += dot4(a1, wA); acc[1][1] += dot4(a1, wB);
      acc[2][0] += dot4(a2, wA); acc[2][1] += dot4(a2, wB);
      acc[3][0] += dot4(a3, wA); acc[3][1] += dot4(a3, wB);
    }

    int jA = (p << 6) + lane;
    int jB = jA + 32;
    float bA = bias[jA];
    float bB = bias[jB];
#pragma unroll
    for (int r = 0; r < 4; ++r) {
      int node = rbase + r;
      float nv = nin[node];
      float oA = (acc[r][0] + bA) * nv;
      float oB = (acc[r][1] + bB) * nv;
      if (mode) {
        oA += resid[node * DD + jA];
        oB += resid[node * DD + jB];
        oA = fmaxf(oA, 0.f);
        oB = fmaxf(oB, 0.f);
      }
      outp[node * DD + jA] = oA;
      outp[node * DD + jB] = oB;
    }
  }
}

extern "C" void kernel_launch(void* const* d_in, const int* in_sizes, int n_in,
                              void* d_out, int out_size, void* d_ws, size_t ws_size,
                              hipStream_t stream) {
  const float* feat = (const float*)d_in[0];
  const int* src = (const int*)d_in[1];
  const int* dst = (const int*)d_in[2];
  const float* W1 = (const float*)d_in[3];
  const float* b1 = (const float*)d_in[4];
  const float* W2 = (const float*)d_in[5];
  const float* b2 = (const float*)d_in[6];
  const float* W3 = (const float*)d_in[7];
  const float* b3 = (const float*)d_in[8];
  float* out = (float*)d_out;

  // workspace layout (first three arrays contiguous for one memset)
  int* cnt_src = (int*)d_ws;             // N
  int* cnt_dst = cnt_src + NN;           // N
  int* cursor = cnt_dst + NN;            // N
  int* excl = cursor + NN;               // N
  int* bsums = excl + NN;                // 128
  float* norm_out = (float*)(bsums + 128);  // N
  float* norm_in = norm_out + NN;           // N
  int* csr = (int*)(norm_in + NN);          // E
  float* agg = (float*)(csr + EE);          // N*D (16B-aligned: prefix is 8800512 B)

  hipMemsetAsync(d_ws, 0, (size_t)3 * NN * sizeof(int), stream);

  count_k<<<(EE + 255) / 256, 256, 0, stream>>>(src, dst, cnt_src, cnt_dst);
  norm_k<<<(NN + 255) / 256, 256, 0, stream>>>(cnt_src, cnt_dst, norm_out, norm_in);
  scan1_k<<<98, 256, 0, stream>>>(cnt_dst, excl, bsums);
  scan2_k<<<1, 128, 0, stream>>>(bsums);
  fill_k<<<(EE + 255) / 256, 256, 0, stream>>>(src, dst, excl, bsums, cursor, csr);

  // layer 1: feat -> agg ; gemm in-place on agg, residual=feat, relu
  aggregate_k<<<12500, 256, 0, stream>>>(feat, norm_out, csr, excl, bsums, agg);
  gemm_k<<<3125, 256, 0, stream>>>(agg, W1, b1, norm_in, feat, agg, 1);
  // layer 2: agg -> out ; gemm in-place on out, residual=agg, relu
  aggregate_k<<<12500, 256, 0, stream>>>(agg, norm_out, csr, excl, bsums, out);
  gemm_k<<<3125, 256, 0, stream>>>(out, W2, b2, norm_in, agg, out, 1);
  // layer 3: out -> agg ; gemm agg -> out, no residual, no act
  aggregate_k<<<12500, 256, 0, stream>>>(out, norm_out, csr, excl, bsums, agg);
  gemm_k<<<3125, 256, 0, stream>>>(agg, W3, b3, norm_in, nullptr, out, 0);
}